// Round 7
// baseline (516.688 us; speedup 1.0000x reference)
//
#include <hip/hip_runtime.h>

#define BB 4
#define TT 32
#define DD 256
#define NN 1024

// ws layout (float indices). Total 819200 floats = 3.28 MB (exactly the R3-proven size).
// p slots are WRITE-ONCE per launch (full per-step buffers, no ring -> no lapping).
// Validity via embedded seq tag; 0xAA poison / garbage never matches (collision ~2^-32/slot).
#define XN_OFF  0        // xn [4][32][1024] f32
#define TN_OFF  131072   // tn [4][32][1024] f32  (tn[b][t] = tgt_neurons[b][t+1]; [31] unused)
#define P64_OFF 262144   // p u64 [B*T][2][1024]: (value_f32<<32)|seq, seq = bt*2+phase+1 (1..256)
#define YW_OFF  786432   // yw [B*T][256] f32 accumulator (memset 0 each launch)

// ---------------- kernel 1: xn = relu(LN(x @ E)), tn shifted; grid = 64 ----------------
__global__ __launch_bounds__(256) void precompute_kernel(
    const float* __restrict__ x_seq, const float* __restrict__ targets,
    const float* __restrict__ E, float* __restrict__ ws)
{
    __shared__ float xr[4][DD];
    __shared__ float redS[4][4], redSS[4][4];
    const int blk = blockIdx.x;        // 0..63
    const int bt0 = blk * 2, bt1 = bt0 + 1;
    const int tid = threadIdx.x;
    const int lane = tid & 63, w = tid >> 6;

    xr[0][tid] = x_seq[(size_t)bt0 * DD + tid];
    xr[1][tid] = x_seq[(size_t)bt1 * DD + tid];
    xr[2][tid] = targets[(size_t)bt0 * DD + tid];
    xr[3][tid] = targets[(size_t)bt1 * DD + tid];
    __syncthreads();

    const float4* E4 = (const float4*)E;
    float4 acc[4];
#pragma unroll
    for (int r = 0; r < 4; ++r) acc[r] = make_float4(0.f, 0.f, 0.f, 0.f);
#pragma unroll 4
    for (int k = 0; k < DD; ++k) {
        float4 e = E4[(size_t)k * (NN / 4) + tid];
#pragma unroll
        for (int r = 0; r < 4; ++r) {
            float xv = xr[r][k];
            acc[r].x += xv * e.x; acc[r].y += xv * e.y;
            acc[r].z += xv * e.z; acc[r].w += xv * e.w;
        }
    }
    float s[4], ss[4];
#pragma unroll
    for (int r = 0; r < 4; ++r) {
        s[r]  = acc[r].x + acc[r].y + acc[r].z + acc[r].w;
        ss[r] = acc[r].x*acc[r].x + acc[r].y*acc[r].y + acc[r].z*acc[r].z + acc[r].w*acc[r].w;
    }
#pragma unroll
    for (int d = 1; d < 64; d <<= 1) {
#pragma unroll
        for (int r = 0; r < 4; ++r) {
            s[r]  += __shfl_xor(s[r], d, 64);
            ss[r] += __shfl_xor(ss[r], d, 64);
        }
    }
    if (lane == 0) {
#pragma unroll
        for (int r = 0; r < 4; ++r) { redS[w][r] = s[r]; redSS[w][r] = ss[r]; }
    }
    __syncthreads();
#pragma unroll
    for (int r = 0; r < 4; ++r) {
        s[r]  = redS[0][r] + redS[1][r] + redS[2][r] + redS[3][r];
        ss[r] = redSS[0][r] + redSS[1][r] + redSS[2][r] + redSS[3][r];
    }
#pragma unroll
    for (int r = 0; r < 4; ++r) {
        const float mu  = s[r] * (1.0f / NN);
        const float var = ss[r] * (1.0f / NN) - mu * mu;
        const float inv = rsqrtf(var + 1e-5f);
        float4 o;
        o.x = fmaxf(0.f, (acc[r].x - mu) * inv);
        o.y = fmaxf(0.f, (acc[r].y - mu) * inv);
        o.z = fmaxf(0.f, (acc[r].z - mu) * inv);
        o.w = fmaxf(0.f, (acc[r].w - mu) * inv);
        const int bt = (r & 1) ? bt1 : bt0;
        float* dst = nullptr;
        if (r < 2) dst = ws + XN_OFF + (size_t)bt * NN;
        else if ((bt & 31) > 0) dst = ws + TN_OFF + (size_t)(bt - 1) * NN;
        if (dst) ((float4*)dst)[tid] = o;
    }
}

// ---------------- kernel 2: fence-free 3-stage pipeline, write-once slots ----------------
__device__ __forceinline__ unsigned long long ld_slot(const unsigned long long* p) {
    return __hip_atomic_load(p, __ATOMIC_RELAXED, __HIP_MEMORY_SCOPE_AGENT);
}
__device__ __forceinline__ void st_slot(unsigned long long* p, unsigned long long v) {
    __hip_atomic_store(p, v, __ATOMIC_RELAXED, __HIP_MEMORY_SCOPE_AGENT);
}
__device__ __forceinline__ float poll1(const unsigned long long* p, unsigned seq) {
    unsigned long long u; int g = 0;
    do {
        u = ld_slot(p);
        if ((unsigned)u == seq) break;
        __builtin_amdgcn_s_sleep(1);
    } while (++g < (1 << 20));
    return __uint_as_float((unsigned)(u >> 32));
}

__global__ __launch_bounds__(512, 2) void mega_kernel(
    const float* __restrict__ Dy, float* __restrict__ ws)
{
    __shared__ float r_lds[64];
    const int blk   = blockIdx.x;      // 0..191
    const int stage = blk >> 6;        // 0,1,2
    const int b     = (blk >> 4) & 3;
    const int wg    = blk & 15;
    const int tid   = threadIdx.x;
    const int lane  = tid & 63;
    const int w     = tid >> 6;
    const int colbase = wg * 64 + w * 8;   // wave owns cols colbase..+7
    const int row0    = lane * 16;         // lane owns rows row0..+15

    const float* xn = ws + XN_OFF + (size_t)b * TT * NN;
    const float* tn = ws + TN_OFF + (size_t)b * TT * NN;
    unsigned long long* pb = (unsigned long long*)(ws + P64_OFF);
    float* yw = ws + YW_OFF;

    float G[16][8];
#pragma unroll
    for (int i = 0; i < 16; ++i)
#pragma unroll
        for (int c = 0; c < 8; ++c)
            G[i][c] = (row0 + i == colbase + c) ? 0.01f : 0.0f;

#pragma unroll 1
    for (int t = 0; t < TT; ++t) {
        const int bt = b * TT + t;
        unsigned long long* p1 = pb + (size_t)bt * 2 * NN;   // write-once: no lapping possible
        unsigned long long* p2 = p1 + NN;
        const unsigned seq1 = (unsigned)(bt * 2 + 1);
        const unsigned seq2 = (unsigned)(bt * 2 + 2);

        float in[16], x[16];
        if (stage == 0) {
            const float4* xp = (const float4*)(xn + (size_t)t * NN + row0);
            float4 q0 = xp[0], q1 = xp[1], q2 = xp[2], q3 = xp[3];
            in[0]=q0.x; in[1]=q0.y; in[2]=q0.z; in[3]=q0.w;
            in[4]=q1.x; in[5]=q1.y; in[6]=q1.z; in[7]=q1.w;
            in[8]=q2.x; in[9]=q2.y; in[10]=q2.z; in[11]=q2.w;
            in[12]=q3.x; in[13]=q3.y; in[14]=q3.z; in[15]=q3.w;
#pragma unroll
            for (int j = 0; j < 16; ++j) x[j] = in[j];
        } else {
            // poll own 16 row slots; exactly-once consume; s_sleep backoff on miss
            const unsigned long long* src = ((stage == 1) ? p1 : p2) + row0;
            const unsigned sq = (stage == 1) ? seq1 : seq2;
            unsigned long long vb[16];
            bool ok = false; int guard = 0;
            while (true) {
                if (!ok) {
                    ok = true;
#pragma unroll
                    for (int j = 0; j < 16; ++j) {
                        vb[j] = ld_slot(src + j);
                        ok &= ((unsigned)vb[j] == sq);
                    }
                }
                if (__all(ok)) break;
                if (++guard > (1 << 20)) break;   // fail visibly, never hang
                __builtin_amdgcn_s_sleep(4);
            }
#pragma unroll
            for (int j = 0; j < 16; ++j) in[j] = __uint_as_float((unsigned)(vb[j] >> 32));
        }

        // matvec partials over this lane's 16 rows
        float acc[8] = {0.f,0.f,0.f,0.f,0.f,0.f,0.f,0.f};
#pragma unroll
        for (int i = 0; i < 16; ++i)
#pragma unroll
            for (int c = 0; c < 8; ++c) acc[c] += in[i] * G[i][c];

        // reduce-scatter (xor 4/2/1) then butterfly (xor 8/16/32):
        // every lane ends with the full sum for col colbase + (lane&7)
        float t4[8];
#pragma unroll
        for (int c = 0; c < 8; ++c) t4[c] = __shfl_xor(acc[c], 4, 64);
        const bool k2 = (lane & 4) != 0;
        float s4[4];
#pragma unroll
        for (int k = 0; k < 4; ++k) s4[k] = k2 ? (acc[4+k] + t4[4+k]) : (acc[k] + t4[k]);
        float t2[4];
#pragma unroll
        for (int k = 0; k < 4; ++k) t2[k] = __shfl_xor(s4[k], 2, 64);
        const bool k1 = (lane & 2) != 0;
        float s2[2];
#pragma unroll
        for (int k = 0; k < 2; ++k) s2[k] = k1 ? (s4[2+k] + t2[2+k]) : (s4[k] + t2[k]);
        float t1[2];
#pragma unroll
        for (int k = 0; k < 2; ++k) t1[k] = __shfl_xor(s2[k], 1, 64);
        float v = (lane & 1) ? (s2[1] + t1[1]) : (s2[0] + t1[0]);
        v += __shfl_xor(v, 8, 64);
        v += __shfl_xor(v, 16, 64);
        v += __shfl_xor(v, 32, 64);

        if (stage == 0) {
            if (lane < 8)
                st_slot(p1 + colbase + lane,
                        ((unsigned long long)__float_as_uint(v) << 32) | seq1);
        } else if (stage == 1) {
            if (lane < 8)
                st_slot(p2 + colbase + lane,
                        ((unsigned long long)__float_as_uint(v) << 32) | seq2);
        } else {
            // r = max(p1,p2,p3) at own col; then y partial for owned 64 cols
            float v1own = poll1(p1 + colbase + (lane & 7), seq1);
            float v2own = poll1(p2 + colbase + (lane & 7), seq2);
            float r = fmaxf(v, fmaxf(v1own, v2own));
            if (lane < 8) r_lds[w * 8 + lane] = r;
            __syncthreads();
            {
                const int d = tid & 255;
                const int h = tid >> 8;
                float a = 0.f;
#pragma unroll
                for (int j = 0; j < 32; ++j) {
                    const int cl = h * 32 + j;
                    a += r_lds[cl] * Dy[(size_t)(wg * 64 + cl) * DD + d];
                }
                atomicAdd(&yw[(size_t)bt * DD + d], a);
            }
            __syncthreads();  // r_lds reused next iteration
        }

        // G update: G = max(G, 0.5*xn_t*tn_t^T), skip last step
        if (t < TT - 1) {
            if (stage != 0) {
                const float4* xp = (const float4*)(xn + (size_t)t * NN + row0);
                float4 q0 = xp[0], q1 = xp[1], q2 = xp[2], q3 = xp[3];
                x[0]=q0.x; x[1]=q0.y; x[2]=q0.z; x[3]=q0.w;
                x[4]=q1.x; x[5]=q1.y; x[6]=q1.z; x[7]=q1.w;
                x[8]=q2.x; x[9]=q2.y; x[10]=q2.z; x[11]=q2.w;
                x[12]=q3.x; x[13]=q3.y; x[14]=q3.z; x[15]=q3.w;
            }
            const float4 ta = *(const float4*)(tn + (size_t)t * NN + colbase);
            const float4 tb = *(const float4*)(tn + (size_t)t * NN + colbase + 4);
            const float tv[8] = {0.5f*ta.x, 0.5f*ta.y, 0.5f*ta.z, 0.5f*ta.w,
                                 0.5f*tb.x, 0.5f*tb.y, 0.5f*tb.z, 0.5f*tb.w};
#pragma unroll
            for (int c = 0; c < 8; ++c)
#pragma unroll
                for (int i = 0; i < 16; ++i)
                    G[i][c] = fmaxf(G[i][c], x[i] * tv[c]);
        }
    }
}

// ---------------- kernel 3: final relu ----------------
__global__ __launch_bounds__(256) void relu_out_kernel(
    const float* __restrict__ yw, float* __restrict__ out, int n)
{
    int i = blockIdx.x * blockDim.x + threadIdx.x;
    if (i < n) out[i] = fmaxf(yw[i], 0.0f);
}

extern "C" void kernel_launch(void* const* d_in, const int* in_sizes, int n_in,
                              void* d_out, int out_size, void* d_ws, size_t ws_size,
                              hipStream_t stream) {
    const float* x_seq   = (const float*)d_in[0];
    const float* targets = (const float*)d_in[1];
    const float* E       = (const float*)d_in[2];
    const float* Dy      = (const float*)d_in[3];
    float* out = (float*)d_out;
    float* ws  = (float*)d_ws;

    // zero only the y accumulator; p slots are seq-tag-protected (poison never matches)
    hipMemsetAsync(ws + YW_OFF, 0, (size_t)(BB * TT * DD) * sizeof(float), stream);

    precompute_kernel<<<BB * TT / 2, 256, 0, stream>>>(x_seq, targets, E, ws);
    mega_kernel<<<3 * BB * 16, 512, 0, stream>>>(Dy, ws);
    relu_out_kernel<<<(BB * TT * DD + 255) / 256, 256, 0, stream>>>(ws + YW_OFF, out, BB * TT * DD);
}

// Round 8
// 301.756 us; speedup vs baseline: 1.7123x; 1.7123x over previous
//
#include <hip/hip_runtime.h>

#define BB 4
#define TT 32
#define DD 256
#define NN 1024

// ws layout (float indices). Total 819200 floats = 3.28 MB (R7-proven size).
// p slots WRITE-ONCE per launch (no ring, no lapping). Validity via embedded seq tags;
// counters are only latency HINTS (slots are the truth), so no fences are needed.
#define XN_OFF  0        // xn [4][32][1024] f32
#define TN_OFF  131072   // tn [4][32][1024] f32; rows [b][31] unused by data -> counters
#define P64_OFF 262144   // p u64 [B*T][2][1024]: (value_f32<<32)|seq, seq = bt*2+phase+1
#define YW_OFF  786432   // yw [B*T][256] f32 accumulator (zeroed by precompute)

// counter for (b,t,ph): u32 inside tn row 31 of batch b, padded 16 u32 (64 B) apart
__device__ __forceinline__ unsigned* cnt_ptr(float* ws, int b, int t, int ph) {
    return (unsigned*)(ws + TN_OFF + (size_t)(b * 32 + 31) * NN) + (size_t)(t * 2 + ph) * 16;
}

// ---------------- kernel 1: zero yw+counters; xn = relu(LN(x @ E)), tn shifted ----------------
__global__ __launch_bounds__(256) void precompute_kernel(
    const float* __restrict__ x_seq, const float* __restrict__ targets,
    const float* __restrict__ E, float* __restrict__ ws)
{
    __shared__ float xr[4][DD];
    __shared__ float redS[4][4], redSS[4][4];
    const int blk = blockIdx.x;        // 0..63
    const int bt0 = blk * 2, bt1 = bt0 + 1;
    const int tid = threadIdx.x;
    const int lane = tid & 63, w = tid >> 6;

    // zero yw (512 floats/block) and counter rows (blocks 0..3)
    ((float2*)(ws + YW_OFF))[blk * 256 + tid] = make_float2(0.f, 0.f);
    if (blk < 4) ((float4*)(ws + TN_OFF + (size_t)(blk * 32 + 31) * NN))[tid] =
        make_float4(0.f, 0.f, 0.f, 0.f);

    xr[0][tid] = x_seq[(size_t)bt0 * DD + tid];
    xr[1][tid] = x_seq[(size_t)bt1 * DD + tid];
    xr[2][tid] = targets[(size_t)bt0 * DD + tid];
    xr[3][tid] = targets[(size_t)bt1 * DD + tid];
    __syncthreads();

    const float4* E4 = (const float4*)E;
    float4 acc[4];
#pragma unroll
    for (int r = 0; r < 4; ++r) acc[r] = make_float4(0.f, 0.f, 0.f, 0.f);
#pragma unroll 4
    for (int k = 0; k < DD; ++k) {
        float4 e = E4[(size_t)k * (NN / 4) + tid];
#pragma unroll
        for (int r = 0; r < 4; ++r) {
            float xv = xr[r][k];
            acc[r].x += xv * e.x; acc[r].y += xv * e.y;
            acc[r].z += xv * e.z; acc[r].w += xv * e.w;
        }
    }
    float s[4], ss[4];
#pragma unroll
    for (int r = 0; r < 4; ++r) {
        s[r]  = acc[r].x + acc[r].y + acc[r].z + acc[r].w;
        ss[r] = acc[r].x*acc[r].x + acc[r].y*acc[r].y + acc[r].z*acc[r].z + acc[r].w*acc[r].w;
    }
#pragma unroll
    for (int d = 1; d < 64; d <<= 1) {
#pragma unroll
        for (int r = 0; r < 4; ++r) {
            s[r]  += __shfl_xor(s[r], d, 64);
            ss[r] += __shfl_xor(ss[r], d, 64);
        }
    }
    if (lane == 0) {
#pragma unroll
        for (int r = 0; r < 4; ++r) { redS[w][r] = s[r]; redSS[w][r] = ss[r]; }
    }
    __syncthreads();
#pragma unroll
    for (int r = 0; r < 4; ++r) {
        s[r]  = redS[0][r] + redS[1][r] + redS[2][r] + redS[3][r];
        ss[r] = redSS[0][r] + redSS[1][r] + redSS[2][r] + redSS[3][r];
    }
#pragma unroll
    for (int r = 0; r < 4; ++r) {
        const float mu  = s[r] * (1.0f / NN);
        const float var = ss[r] * (1.0f / NN) - mu * mu;
        const float inv = rsqrtf(var + 1e-5f);
        float4 o;
        o.x = fmaxf(0.f, (acc[r].x - mu) * inv);
        o.y = fmaxf(0.f, (acc[r].y - mu) * inv);
        o.z = fmaxf(0.f, (acc[r].z - mu) * inv);
        o.w = fmaxf(0.f, (acc[r].w - mu) * inv);
        const int bt = (r & 1) ? bt1 : bt0;
        float* dst = nullptr;
        if (r < 2) dst = ws + XN_OFF + (size_t)bt * NN;
        else if ((bt & 31) > 0) dst = ws + TN_OFF + (size_t)(bt - 1) * NN;
        if (dst) ((float4*)dst)[tid] = o;
    }
}

// ---------------- kernel 2: fence-free pipeline; counter hints, tag-verified data ----------------
__device__ __forceinline__ unsigned long long ld_slot(const unsigned long long* p) {
    return __hip_atomic_load(p, __ATOMIC_RELAXED, __HIP_MEMORY_SCOPE_AGENT);
}
__device__ __forceinline__ void st_slot(unsigned long long* p, unsigned long long v) {
    __hip_atomic_store(p, v, __ATOMIC_RELAXED, __HIP_MEMORY_SCOPE_AGENT);
}
__device__ __forceinline__ float poll1(const unsigned long long* p, unsigned seq) {
    unsigned long long u; int g = 0;
    do {
        u = ld_slot(p);
        if ((unsigned)u == seq) break;
        __builtin_amdgcn_s_sleep(1);
    } while (++g < (1 << 20));
    return __uint_as_float((unsigned)(u >> 32));
}

__global__ __launch_bounds__(512, 2) void mega_kernel(
    const float* __restrict__ Dy, float* __restrict__ ws)
{
    __shared__ float sh[NN + NN / 16];   // padded p-vector staging
    __shared__ float r_lds[64];
    const int blk   = blockIdx.x;      // 0..191
    const int stage = blk >> 6;        // 0,1,2
    const int b     = (blk >> 4) & 3;
    const int wg    = blk & 15;
    const int tid   = threadIdx.x;
    const int lane  = tid & 63;
    const int w     = tid >> 6;
    const int colbase = wg * 64 + w * 8;   // wave owns cols colbase..+7
    const int row0    = lane * 16;         // lane owns rows row0..+15

    const float* xn = ws + XN_OFF + (size_t)b * TT * NN;
    const float* tn = ws + TN_OFF + (size_t)b * TT * NN;
    unsigned long long* pb = (unsigned long long*)(ws + P64_OFF);
    float* yw = ws + YW_OFF;

    float G[16][8];
#pragma unroll
    for (int i = 0; i < 16; ++i)
#pragma unroll
        for (int c = 0; c < 8; ++c)
            G[i][c] = (row0 + i == colbase + c) ? 0.01f : 0.0f;

#pragma unroll 1
    for (int t = 0; t < TT; ++t) {
        const int bt = b * TT + t;
        unsigned long long* p1 = pb + (size_t)bt * 2 * NN;   // write-once
        unsigned long long* p2 = p1 + NN;
        const unsigned seq1 = (unsigned)(bt * 2 + 1);
        const unsigned seq2 = (unsigned)(bt * 2 + 2);

        float in[16], x[16];
        if (stage == 0) {
            const float4* xp = (const float4*)(xn + (size_t)t * NN + row0);
            float4 q0 = xp[0], q1 = xp[1], q2 = xp[2], q3 = xp[3];
            in[0]=q0.x; in[1]=q0.y; in[2]=q0.z; in[3]=q0.w;
            in[4]=q1.x; in[5]=q1.y; in[6]=q1.z; in[7]=q1.w;
            in[8]=q2.x; in[9]=q2.y; in[10]=q2.z; in[11]=q2.w;
            in[12]=q3.x; in[13]=q3.y; in[14]=q3.z; in[15]=q3.w;
#pragma unroll
            for (int j = 0; j < 16; ++j) x[j] = in[j];
        } else {
            // hint: tid0-only relaxed counter poll (stale/poison counter -> early fall-through;
            // the tag-verified read below is the actual synchronization)
            const unsigned* cp = cnt_ptr(ws, b, t, stage - 1);
            if (tid == 0) {
                int g = 0;
                while (__hip_atomic_load(cp, __ATOMIC_RELAXED, __HIP_MEMORY_SCOPE_AGENT) < 16u) {
                    __builtin_amdgcn_s_sleep(2);
                    if (++g > (1 << 20)) break;
                }
            }
            __syncthreads();   // also protects sh[] reuse from previous iteration

            // one cooperative tag-verified read of the 1024-slot vector -> padded LDS
            const unsigned long long* src = (stage == 1) ? p1 : p2;
            const unsigned sq = (stage == 1) ? seq1 : seq2;
            unsigned long long va, vb2; bool oka = false, okb = false; int guard = 0;
            while (true) {
                if (!oka) { va  = ld_slot(src + tid);       oka = ((unsigned)va  == sq); }
                if (!okb) { vb2 = ld_slot(src + tid + 512); okb = ((unsigned)vb2 == sq); }
                if (__all(oka && okb)) break;
                if (++guard > (1 << 20)) break;   // fail visibly, never hang
                __builtin_amdgcn_s_sleep(2);
            }
            sh[tid + (tid >> 4)] = __uint_as_float((unsigned)(va >> 32));
            const int i2 = tid + 512;
            sh[i2 + (i2 >> 4)] = __uint_as_float((unsigned)(vb2 >> 32));
            __syncthreads();
#pragma unroll
            for (int j = 0; j < 16; ++j) in[j] = sh[lane * 17 + j];
        }

        // matvec partials over this lane's 16 rows
        float acc[8] = {0.f,0.f,0.f,0.f,0.f,0.f,0.f,0.f};
#pragma unroll
        for (int i = 0; i < 16; ++i)
#pragma unroll
            for (int c = 0; c < 8; ++c) acc[c] += in[i] * G[i][c];

        // reduce-scatter (xor 4/2/1) then butterfly (xor 8/16/32)
        float t4[8];
#pragma unroll
        for (int c = 0; c < 8; ++c) t4[c] = __shfl_xor(acc[c], 4, 64);
        const bool k2 = (lane & 4) != 0;
        float s4[4];
#pragma unroll
        for (int k = 0; k < 4; ++k) s4[k] = k2 ? (acc[4+k] + t4[4+k]) : (acc[k] + t4[k]);
        float t2[4];
#pragma unroll
        for (int k = 0; k < 4; ++k) t2[k] = __shfl_xor(s4[k], 2, 64);
        const bool k1 = (lane & 2) != 0;
        float s2[2];
#pragma unroll
        for (int k = 0; k < 2; ++k) s2[k] = k1 ? (s4[2+k] + t2[2+k]) : (s4[k] + t2[k]);
        float t1[2];
#pragma unroll
        for (int k = 0; k < 2; ++k) t1[k] = __shfl_xor(s2[k], 1, 64);
        float v = (lane & 1) ? (s2[1] + t1[1]) : (s2[0] + t1[0]);
        v += __shfl_xor(v, 8, 64);
        v += __shfl_xor(v, 16, 64);
        v += __shfl_xor(v, 32, 64);

        if (stage == 0) {
            if (lane < 8)
                st_slot(p1 + colbase + lane,
                        ((unsigned long long)__float_as_uint(v) << 32) | seq1);
            __syncthreads();   // all waves' slot stores drained (vmcnt 0 at barrier)
            if (tid == 0)
                __hip_atomic_fetch_add(cnt_ptr(ws, b, t, 0), 1u,
                                       __ATOMIC_RELAXED, __HIP_MEMORY_SCOPE_AGENT);
        } else if (stage == 1) {
            if (lane < 8)
                st_slot(p2 + colbase + lane,
                        ((unsigned long long)__float_as_uint(v) << 32) | seq2);
            __syncthreads();
            if (tid == 0)
                __hip_atomic_fetch_add(cnt_ptr(ws, b, t, 1), 1u,
                                       __ATOMIC_RELAXED, __HIP_MEMORY_SCOPE_AGENT);
        } else {
            // r = max(p1,p2,p3) at own col; p2[own] from LDS, p1[own] via tiny poll
            const int colg = colbase + (lane & 7);
            float v2own = sh[colg + (colg >> 4)];
            float v1own = poll1(p1 + colg, seq1);
            float r = fmaxf(v, fmaxf(v1own, v2own));
            if (lane < 8) r_lds[w * 8 + lane] = r;
            __syncthreads();
            {
                const int d = tid & 255;
                const int h = tid >> 8;
                float a = 0.f;
#pragma unroll
                for (int j = 0; j < 32; ++j) {
                    const int cl = h * 32 + j;
                    a += r_lds[cl] * Dy[(size_t)(wg * 64 + cl) * DD + d];
                }
                atomicAdd(&yw[(size_t)bt * DD + d], a);
            }
        }

        // G update: G = max(G, 0.5*xn_t*tn_t^T), skip last step
        if (t < TT - 1) {
            if (stage != 0) {
                const float4* xp = (const float4*)(xn + (size_t)t * NN + row0);
                float4 q0 = xp[0], q1 = xp[1], q2 = xp[2], q3 = xp[3];
                x[0]=q0.x; x[1]=q0.y; x[2]=q0.z; x[3]=q0.w;
                x[4]=q1.x; x[5]=q1.y; x[6]=q1.z; x[7]=q1.w;
                x[8]=q2.x; x[9]=q2.y; x[10]=q2.z; x[11]=q2.w;
                x[12]=q3.x; x[13]=q3.y; x[14]=q3.z; x[15]=q3.w;
            }
            const float4 ta = *(const float4*)(tn + (size_t)t * NN + colbase);
            const float4 tb = *(const float4*)(tn + (size_t)t * NN + colbase + 4);
            const float tv[8] = {0.5f*ta.x, 0.5f*ta.y, 0.5f*ta.z, 0.5f*ta.w,
                                 0.5f*tb.x, 0.5f*tb.y, 0.5f*tb.z, 0.5f*tb.w};
#pragma unroll
            for (int c = 0; c < 8; ++c)
#pragma unroll
                for (int i = 0; i < 16; ++i)
                    G[i][c] = fmaxf(G[i][c], x[i] * tv[c]);
        }
    }
}

// ---------------- kernel 3: final relu ----------------
__global__ __launch_bounds__(256) void relu_out_kernel(
    const float* __restrict__ yw, float* __restrict__ out, int n)
{
    int i = blockIdx.x * blockDim.x + threadIdx.x;
    if (i < n) out[i] = fmaxf(yw[i], 0.0f);
}

extern "C" void kernel_launch(void* const* d_in, const int* in_sizes, int n_in,
                              void* d_out, int out_size, void* d_ws, size_t ws_size,
                              hipStream_t stream) {
    const float* x_seq   = (const float*)d_in[0];
    const float* targets = (const float*)d_in[1];
    const float* E       = (const float*)d_in[2];
    const float* Dy      = (const float*)d_in[3];
    float* out = (float*)d_out;
    float* ws  = (float*)d_ws;

    // 3 nodes only: precompute zeroes yw+counters itself; p slots are tag-protected.
    precompute_kernel<<<BB * TT / 2, 256, 0, stream>>>(x_seq, targets, E, ws);
    mega_kernel<<<3 * BB * 16, 512, 0, stream>>>(Dy, ws);
    relu_out_kernel<<<(BB * TT * DD + 255) / 256, 256, 0, stream>>>(ws + YW_OFF, out, BB * TT * DD);
}